// Round 13
// baseline (232.605 us; speedup 1.0000x reference)
//
#include <hip/hip_runtime.h>
#include <cmath>

#define NEG 0.2f

typedef __bf16 bf16x8 __attribute__((ext_vector_type(8)));
typedef float  f32x4  __attribute__((ext_vector_type(4)));

__device__ __forceinline__ void async16(const __bf16* g, __bf16* l) {
  __builtin_amdgcn_global_load_lds(
      (const __attribute__((address_space(1))) void*)g,
      (__attribute__((address_space(3))) void*)l, 16, 0, 0);
}
__device__ __forceinline__ f32x4 mfma16(bf16x8 a, bf16x8 b, f32x4 c) {
  return __builtin_amdgcn_mfma_f32_16x16x32_bf16(a, b, c, 0, 0, 0);
}

// ---------------- CSR build ----------------
__global__ void count_kernel(const int* __restrict__ ei, int* __restrict__ counts, int E, int Nn) {
  int e = blockIdx.x * blockDim.x + threadIdx.x;
  if (e >= E + Nn) return;
  int d = (e < E) ? ei[E + e] : (e - E);
  atomicAdd(&counts[d], 1);
}

__global__ __launch_bounds__(1024) void scan_kernel(const int* __restrict__ counts,
                                                    int* __restrict__ row_ptr,
                                                    int* __restrict__ cursor,
                                                    int n, int total) {
  __shared__ int sums[1024];
  int t = threadIdx.x;
  int per = (n + 1023) >> 10;
  int base = t * per;
  int s = 0;
  for (int i = 0; i < per; ++i) { int idx = base + i; if (idx < n) s += counts[idx]; }
  sums[t] = s;
  __syncthreads();
  for (int st = 1; st < 1024; st <<= 1) {
    int v = (t >= st) ? sums[t - st] : 0;
    __syncthreads();
    sums[t] += v;
    __syncthreads();
  }
  int off = (t == 0) ? 0 : sums[t - 1];
  for (int i = 0; i < per; ++i) {
    int idx = base + i;
    if (idx < n) { row_ptr[idx] = off; cursor[idx] = off; off += counts[idx]; }
  }
  if (t == 0) row_ptr[n] = total;
}

__global__ void scatter_kernel(const int* __restrict__ ei, int* __restrict__ cursor,
                               int* __restrict__ src_sorted, int E, int Nn) {
  int e = blockIdx.x * blockDim.x + threadIdx.x;
  if (e >= E + Nn) return;
  int s, d;
  if (e < E) { s = ei[e]; d = ei[E + e]; } else { s = e - E; d = e - E; }
  int pos = atomicAdd(&cursor[d], 1);
  src_sorted[pos] = s;
}

// ------- fused prep: zero counts, split x, transpose W1/W2/W3 (high only) ----
__global__ void prep_kernel(const float* __restrict__ x, __bf16* __restrict__ xsh,
                            __bf16* __restrict__ xsl,
                            const float* __restrict__ W1, __bf16* __restrict__ W1th,
                            const float* __restrict__ W2, __bf16* __restrict__ W2th,
                            const float* __restrict__ W3, __bf16* __restrict__ W3th,
                            int* __restrict__ counts, int Nn) {
  int i = blockIdx.x * blockDim.x + threadIdx.x;
  if (i < Nn) { counts[i] = 0; return; }
  i -= Nn;
  int nx = Nn * 256;
  if (i < nx) {
    float v = x[i];
    __bf16 h = (__bf16)v;
    xsh[i] = h;
    xsl[i] = (__bf16)(v - (float)h);
    return;
  }
  i -= nx;
  if (i < 256 * 512) {
    int k = i / 512, c = i % 512;
    W1th[(size_t)c * 256 + k] = (__bf16)W1[i];
    return;
  }
  i -= 256 * 512;
  if (i < 512 * 512) {
    int k = i / 512, c = i % 512;
    W2th[(size_t)c * 512 + k] = (__bf16)W2[i];
    return;
  }
  i -= 512 * 512;
  if (i < 512 * 64) {
    int k = i / 64, c = i % 64;
    W3th[(size_t)c * 512 + k] = (__bf16)W3[i];
    return;
  }
}

// ------- bf16 MFMA GEMM v3: BM=64, BN=128 (two heads), fused alpha -----------
template <bool ASPLIT>
__global__ __launch_bounds__(256, 4) void gemm_v3(
    const __bf16* __restrict__ Ah, const __bf16* __restrict__ Al,
    const __bf16* __restrict__ Bth,
    __bf16* __restrict__ Cb,
    const float* __restrict__ asrc, const float* __restrict__ adst,
    float* __restrict__ als, float* __restrict__ ald,
    int M, int K, int Nc, int PX) {
  __shared__ __bf16 sAh[64 * 64], sBh[128 * 64];
  __shared__ __bf16 sAl[ASPLIT ? 64 * 64 : 64];

  int p = blockIdx.x;          // XCD = p%8 (round-robin dispatch)
  int c = p & 7, j = p >> 3;   // row-panels c*PX.. pinned to XCD c
  int x = c * PX + (j >> 2);
  int y = j & 3;
  int rowBase = x * 64, colBase = y * 128;
  if (rowBase >= M) return;

  int tid = threadIdx.x;
  int lane = tid & 63, wave = tid >> 6;
  int r16 = lane & 15, koct = lane >> 4, msk = r16 & 7;

  int fa0 = tid, fa1 = 256 + tid;
  int ar0 = fa0 >> 3, ar1 = fa1 >> 3;
  int as0 = (fa0 & 7) ^ (ar0 & 7);
  int as1 = (fa1 & 7) ^ (ar1 & 7);
  size_t aoff0 = (size_t)min(rowBase + ar0, M - 1) * K + as0 * 8;
  size_t aoff1 = (size_t)min(rowBase + ar1, M - 1) * K + as1 * 8;
  size_t boff[4];
#pragma unroll
  for (int r = 0; r < 4; ++r) {
    int f = r * 256 + tid;
    int col = f >> 3;
    int s = (f & 7) ^ (col & 7);
    boff[r] = (size_t)(colBase + col) * K + s * 8;
  }
  int lb0 = (wave * 64) * 8;
  int lb1 = ((256 + wave * 64)) * 8;
  int lb2 = ((512 + wave * 64)) * 8;
  int lb3 = ((768 + wave * 64)) * 8;

  int arow = wave * 16 + r16;
  f32x4 acc[8] = {};

  for (int k0 = 0; k0 < K; k0 += 64) {
    __syncthreads();
    async16(Ah + aoff0 + k0, sAh + lb0);
    async16(Ah + aoff1 + k0, sAh + lb1);
    if (ASPLIT) {
      async16(Al + aoff0 + k0, sAl + lb0);
      async16(Al + aoff1 + k0, sAl + lb1);
    }
    async16(Bth + boff[0] + k0, sBh + lb0);
    async16(Bth + boff[1] + k0, sBh + lb1);
    async16(Bth + boff[2] + k0, sBh + lb2);
    async16(Bth + boff[3] + k0, sBh + lb3);
    __syncthreads();

#pragma unroll
    for (int kk = 0; kk < 2; ++kk) {
      int ks = ((kk * 4 + koct) ^ msk) * 8;
      bf16x8 ah = *reinterpret_cast<const bf16x8*>(sAh + arow * 64 + ks);
      bf16x8 al;
      if (ASPLIT) al = *reinterpret_cast<const bf16x8*>(sAl + arow * 64 + ks);
      bf16x8 bh[8];
#pragma unroll
      for (int fn = 0; fn < 8; ++fn)
        bh[fn] = *reinterpret_cast<const bf16x8*>(sBh + (fn * 16 + r16) * 64 + ks);
#pragma unroll
      for (int fn = 0; fn < 8; ++fn) {
        acc[fn] = mfma16(ah, bh[fn], acc[fn]);
        if (ASPLIT) acc[fn] = mfma16(al, bh[fn], acc[fn]);
      }
    }
  }

  float asv[8], adv[8];
#pragma unroll
  for (int fn = 0; fn < 8; ++fn) {
    int ai = (y * 2 + (fn >> 2)) * 64 + (fn & 3) * 16 + r16;
    asv[fn] = asrc[ai];
    adv[fn] = adst[ai];
  }
#pragma unroll
  for (int r = 0; r < 4; ++r) {
    int row = rowBase + wave * 16 + koct * 4 + r;
    float psA = 0.f, pdA = 0.f, psB = 0.f, pdB = 0.f;
#pragma unroll
    for (int fn = 0; fn < 8; ++fn) {
      float v = acc[fn][r];
      if (row < M) Cb[(size_t)row * Nc + colBase + fn * 16 + r16] = (__bf16)v;
      if (fn < 4) { psA = fmaf(v, asv[fn], psA); pdA = fmaf(v, adv[fn], pdA); }
      else        { psB = fmaf(v, asv[fn], psB); pdB = fmaf(v, adv[fn], pdB); }
    }
#pragma unroll
    for (int sft = 1; sft < 16; sft <<= 1) {
      psA += __shfl_xor(psA, sft); pdA += __shfl_xor(pdA, sft);
      psB += __shfl_xor(psB, sft); pdB += __shfl_xor(pdB, sft);
    }
    if (r16 == 0 && row < M) {
      als[(size_t)row * 8 + y * 2 + 0] = psA;
      ald[(size_t)row * 8 + y * 2 + 0] = pdA;
      als[(size_t)row * 8 + y * 2 + 1] = psB;
      ald[(size_t)row * 8 + y * 2 + 1] = pdB;
    }
  }
}

// ------- bf16 MFMA GEMM v2: BM=128, BN=64, BK=64, 1-pass A — layer 3 ---------
__global__ __launch_bounds__(256, 4) void gemm_v2(
    const __bf16* __restrict__ Ah,
    const __bf16* __restrict__ Bth,
    float* __restrict__ Cf,
    const float* __restrict__ asrc, const float* __restrict__ adst,
    float* __restrict__ als, float* __restrict__ ald,
    int M, int K, int Nc) {
  __shared__ __bf16 sAh[128 * 64], sBh[64 * 64];

  int x = blockIdx.x;
  int rowBase = x * 128, colBase = 0;
  if (rowBase >= M) return;

  int tid = threadIdx.x;
  int lane = tid & 63, wave = tid >> 6;
  int r16 = lane & 15, koct = lane >> 4, msk = r16 & 7;

  f32x4 acc[2][4] = {};

  for (int k0 = 0; k0 < K; k0 += 64) {
    __syncthreads();
#pragma unroll
    for (int r = 0; r < 4; ++r) {
      int flat = r * 256 + tid;
      int row = flat >> 3;
      int grow = rowBase + row;
      if (grow >= M) grow = M - 1;
      int s = (flat & 7) ^ (row & 7);
      size_t go = (size_t)grow * K + k0 + s * 8;
      int lb = (r * 256 + wave * 64) * 8;
      async16(Ah + go, sAh + lb);
    }
#pragma unroll
    for (int r = 0; r < 2; ++r) {
      int flat = r * 256 + tid;
      int col = flat >> 3;
      int s = (flat & 7) ^ (col & 7);
      size_t go = (size_t)(colBase + col) * K + k0 + s * 8;
      int lb = (r * 256 + wave * 64) * 8;
      async16(Bth + go, sBh + lb);
    }
    __syncthreads();

#pragma unroll
    for (int kk = 0; kk < 2; ++kk) {
      bf16x8 ah[2], bh[4];
#pragma unroll
      for (int fm = 0; fm < 2; ++fm) {
        int off = (wave * 32 + fm * 16 + r16) * 64 + (((kk * 4 + koct) ^ msk) * 8);
        ah[fm] = *reinterpret_cast<const bf16x8*>(sAh + off);
      }
#pragma unroll
      for (int fn = 0; fn < 4; ++fn) {
        int off = (fn * 16 + r16) * 64 + (((kk * 4 + koct) ^ msk) * 8);
        bh[fn] = *reinterpret_cast<const bf16x8*>(sBh + off);
      }
#pragma unroll
      for (int fm = 0; fm < 2; ++fm)
#pragma unroll
        for (int fn = 0; fn < 4; ++fn)
          acc[fm][fn] = mfma16(ah[fm], bh[fn], acc[fm][fn]);
    }
  }

  float asv[4], adv[4];
#pragma unroll
  for (int fn = 0; fn < 4; ++fn) {
    asv[fn] = asrc[fn * 16 + r16];
    adv[fn] = adst[fn * 16 + r16];
  }
#pragma unroll
  for (int fm = 0; fm < 2; ++fm)
#pragma unroll
    for (int r = 0; r < 4; ++r) {
      int row = rowBase + wave * 32 + fm * 16 + koct * 4 + r;
      float ps = 0.f, pd = 0.f;
#pragma unroll
      for (int fn = 0; fn < 4; ++fn) {
        float v = acc[fm][fn][r];
        ps = fmaf(v, asv[fn], ps);
        pd = fmaf(v, adv[fn], pd);
        if (row < M) Cf[(size_t)row * Nc + fn * 16 + r16] = v;
      }
#pragma unroll
      for (int sft = 1; sft < 16; sft <<= 1) {
        ps += __shfl_xor(ps, sft);
        pd += __shfl_xor(pd, sft);
      }
      if (r16 == 0 && row < M) {
        als[row] = ps;
        ald[row] = pd;
      }
    }
}

// ------- TEST: XCD-sliced aggregate, 8 heads. Head h == XCD h (blockIdx%8) ---
// Per-XCD working set (H-slice 1.28MB + src_sorted 1.3MB + alpha 0.6MB) fits
// its private 4MB L2 -> gathers are own-L2 hits; HBM fetch ~1x table.
// Wave = 8 edge-slots x 8 col-groups; fixed-shift exp (validated r11).
__global__ __launch_bounds__(256) void agg8s_kernel(const __bf16* __restrict__ Hb, // [N,512]
                                                    const float* __restrict__ als,
                                                    const float* __restrict__ ald,
                                                    const float* __restrict__ bias,
                                                    const int* __restrict__ row_ptr,
                                                    const int* __restrict__ src_sorted,
                                                    __bf16* __restrict__ Oh,       // [N,512]
                                                    int Nn) {
  int head = blockIdx.x & 7;  // == XCD id under round-robin dispatch
  int n = (blockIdx.x >> 3) * 4 + (threadIdx.x >> 6);
  if (n >= Nn) return;
  int lane = threadIdx.x & 63;
  int slot = lane >> 3, cg = lane & 7;
  int start = row_ptr[n], deg = row_ptr[n + 1] - start;
  float aldn = ald[n * 8 + head];
  const __bf16* hcol = Hb + head * 64 + cg * 8;

  float acc[8] = {};
  float ssum = 0.f;
  for (int e0 = 0; e0 < deg; e0 += 8) {
    int idx = src_sorted[start + min(e0 + slot, deg - 1)];
    float l = als[idx * 8 + head] + aldn;
    l = l > 0.f ? l : NEG * l;
    float w = (e0 + slot < deg) ? __expf(fminf(l, 80.f)) : 0.f;
    bf16x8 v = *reinterpret_cast<const bf16x8*>(hcol + (size_t)idx * 512);
    ssum += w;
#pragma unroll
    for (int j = 0; j < 8; ++j) acc[j] = fmaf(w, (float)v[j], acc[j]);
  }
  // reduce across the 8 edge-slots (lane bits 3..5)
#pragma unroll
  for (int s = 8; s < 64; s <<= 1) {
    ssum += __shfl_xor(ssum, s);
#pragma unroll
    for (int j = 0; j < 8; ++j) acc[j] += __shfl_xor(acc[j], s);
  }
  if (slot == 0) {
    float inv = 1.f / (ssum + 1e-16f);
    bf16x8 vh;
#pragma unroll
    for (int j = 0; j < 8; ++j) {
      float v = acc[j] * inv + bias[head * 64 + cg * 8 + j];
      v = v > 0.f ? v : expm1f(v);
      vh[j] = (__bf16)v;
    }
    *reinterpret_cast<bf16x8*>(Oh + (size_t)n * 512 + head * 64 + cg * 8) = vh;
  }
}

// ------- CONTROL: r10 fused aggregate, 8 heads: one WAVE per node ------------
__global__ __launch_bounds__(256) void agg8_kernel(const __bf16* __restrict__ Hb,  // [N,512]
                                                   const float* __restrict__ als,  // [N,8]
                                                   const float* __restrict__ ald,  // [N,8]
                                                   const float* __restrict__ bias, // [512]
                                                   const int* __restrict__ row_ptr,
                                                   const int* __restrict__ src_sorted,
                                                   __bf16* __restrict__ Oh,        // [N,512]
                                                   int Nn) {
  int n = (blockIdx.x * 256 + threadIdx.x) >> 6;
  if (n >= Nn) return;
  int lane = threadIdx.x & 63;
  int hh = lane >> 3;
  int start = row_ptr[n], deg = row_ptr[n + 1] - start;
  float aldn = ald[n * 8 + hh];

  float acc[8] = {};
  float ssum = 0.f;
  float mrun = 0.f;
  const __bf16* hcol = Hb + lane * 8;
  for (int e0 = 0; e0 < deg; e0 += 8) {
    int idx[8];
    float lv[8];
    bf16x8 v[8];
#pragma unroll
    for (int i = 0; i < 8; ++i) {
      int e = e0 + i;
      if (e > deg - 1) e = deg - 1;
      idx[i] = src_sorted[start + e];
    }
#pragma unroll
    for (int i = 0; i < 8; ++i) lv[i] = als[idx[i] * 8 + hh];
#pragma unroll
    for (int i = 0; i < 8; ++i)
      v[i] = *reinterpret_cast<const bf16x8*>(hcol + (size_t)idx[i] * 512);
    float lm = -INFINITY;
#pragma unroll
    for (int i = 0; i < 8; ++i) {
      float l = lv[i] + aldn;
      l = l > 0.f ? l : NEG * l;
      lv[i] = l;
      lm = fmaxf(lm, l);
    }
    if (__builtin_expect(lm > mrun + 24.f, 0)) {
      float sc = __expf(mrun - lm);
      ssum *= sc;
#pragma unroll
      for (int j = 0; j < 8; ++j) acc[j] *= sc;
      mrun = lm;
    }
#pragma unroll
    for (int i = 0; i < 8; ++i) {
      float w = (e0 + i < deg) ? __expf(lv[i] - mrun) : 0.f;
      ssum += w;
#pragma unroll
      for (int j = 0; j < 8; ++j) acc[j] = fmaf(w, (float)v[i][j], acc[j]);
    }
  }

  float inv = 1.f / (ssum + 1e-16f);
  bf16x8 vh;
#pragma unroll
  for (int j = 0; j < 8; ++j) {
    float v = acc[j] * inv + bias[lane * 8 + j];
    v = v > 0.f ? v : expm1f(v);
    vh[j] = (__bf16)v;
  }
  *reinterpret_cast<bf16x8*>(Oh + (size_t)n * 512 + lane * 8) = vh;
}

// ------- fused aggregate (1 head, one-pass) + classifier + log_softmax ------
__global__ __launch_bounds__(256) void agg1cls_kernel(const float* __restrict__ Hf, // [N,64]
                                                      const float* __restrict__ als,
                                                      const float* __restrict__ ald,
                                                      const float* __restrict__ bias,
                                                      const int* __restrict__ row_ptr,
                                                      const int* __restrict__ src_sorted,
                                                      const float* __restrict__ lw,  // [64,2]
                                                      const float* __restrict__ lb,  // [2]
                                                      float* __restrict__ out,       // [N,2]
                                                      int Nn) {
  int n = (blockIdx.x * 256 + threadIdx.x) >> 6;
  if (n >= Nn) return;
  int lane = threadIdx.x & 63;
  int start = row_ptr[n], deg = row_ptr[n + 1] - start;
  float aldn = ald[n];

  float acc = 0.f, ssum = 0.f, mrun = 0.f;
  for (int e0 = 0; e0 < deg; e0 += 8) {
    int idx[8];
    float lv[8], hv[8];
#pragma unroll
    for (int i = 0; i < 8; ++i) {
      int e = e0 + i;
      if (e > deg - 1) e = deg - 1;
      idx[i] = src_sorted[start + e];
    }
#pragma unroll
    for (int i = 0; i < 8; ++i) lv[i] = als[idx[i]];
#pragma unroll
    for (int i = 0; i < 8; ++i) hv[i] = Hf[(size_t)idx[i] * 64 + lane];
    float lm = -INFINITY;
#pragma unroll
    for (int i = 0; i < 8; ++i) {
      float l = lv[i] + aldn;
      l = l > 0.f ? l : NEG * l;
      lv[i] = l;
      lm = fmaxf(lm, l);
    }
    if (__builtin_expect(lm > mrun + 24.f, 0)) {
      float sc = __expf(mrun - lm);
      ssum *= sc;
      acc *= sc;
      mrun = lm;
    }
#pragma unroll
    for (int i = 0; i < 8; ++i) {
      float w = (e0 + i < deg) ? __expf(lv[i] - mrun) : 0.f;
      ssum += w;
      acc = fmaf(w, hv[i], acc);
    }
  }
  float o = acc / (ssum + 1e-16f) + bias[lane];

  float p0 = o * lw[lane * 2 + 0];
  float p1 = o * lw[lane * 2 + 1];
  for (int s = 32; s; s >>= 1) {
    p0 += __shfl_xor(p0, s);
    p1 += __shfl_xor(p1, s);
  }
  if (lane == 0) {
    p0 += lb[0];
    p1 += lb[1];
    float mx = fmaxf(p0, p1);
    float lse = mx + logf(expf(p0 - mx) + expf(p1 - mx));
    out[n * 2 + 0] = p0 - lse;
    out[n * 2 + 1] = p1 - lse;
  }
}

extern "C" void kernel_launch(void* const* d_in, const int* in_sizes, int n_in,
                              void* d_out, int out_size, void* d_ws, size_t ws_size,
                              hipStream_t stream) {
  (void)n_in; (void)out_size; (void)ws_size;
  const float* x     = (const float*)d_in[0];
  const int*   ei    = (const int*)d_in[1];
  const float* W1    = (const float*)d_in[2];
  const float* asrc1 = (const float*)d_in[3];
  const float* adst1 = (const float*)d_in[4];
  const float* b1    = (const float*)d_in[5];
  const float* W2    = (const float*)d_in[6];
  const float* asrc2 = (const float*)d_in[7];
  const float* adst2 = (const float*)d_in[8];
  const float* b2    = (const float*)d_in[9];
  const float* W3    = (const float*)d_in[10];
  const float* asrc3 = (const float*)d_in[11];
  const float* adst3 = (const float*)d_in[12];
  const float* b3    = (const float*)d_in[13];
  const float* linW  = (const float*)d_in[14];
  const float* linb  = (const float*)d_in[15];
  float* out = (float*)d_out;

  int Nn = in_sizes[0] / 256;
  int E  = in_sizes[1] / 2;
  int E2 = E + Nn;

  char* w = (char*)d_ws;
  auto carve = [&](size_t bytes) {
    char* p = w;
    w += (bytes + 63) & ~(size_t)63;
    return p;
  };
  __bf16* xsh  = (__bf16*)carve((size_t)Nn * 256 * 2);
  __bf16* xsl  = (__bf16*)carve((size_t)Nn * 256 * 2);
  __bf16* Ahb  = (__bf16*)carve((size_t)Nn * 512 * 2);
  __bf16* Hb16 = (__bf16*)carve((size_t)Nn * 512 * 2);
  float*  Hb3  = (float*)carve((size_t)Nn * 64 * 4);
  float*  als  = (float*)carve((size_t)Nn * 8 * 4);
  float*  ald  = (float*)carve((size_t)Nn * 8 * 4);
  __bf16* W1th = (__bf16*)carve(256 * 512 * 2);
  __bf16* W2th = (__bf16*)carve(512 * 512 * 2);
  __bf16* W3th = (__bf16*)carve(512 * 64 * 2);
  int* counts     = (int*)carve((size_t)Nn * 4);
  int* cursor     = (int*)carve((size_t)Nn * 4);
  int* row_ptr    = (int*)carve(((size_t)Nn + 1) * 4);
  int* src_sorted = (int*)carve((size_t)E2 * 4);

  int prep_total = Nn + Nn * 256 + 256 * 512 + 512 * 512 + 512 * 64;
  prep_kernel<<<(prep_total + 255) / 256, 256, 0, stream>>>(
      x, xsh, xsl, W1, W1th, W2, W2th, W3, W3th, counts, Nn);
  count_kernel<<<(E2 + 255) / 256, 256, 0, stream>>>(ei, counts, E, Nn);
  scan_kernel<<<1, 1024, 0, stream>>>(counts, row_ptr, cursor, Nn, E2);
  scatter_kernel<<<(E2 + 255) / 256, 256, 0, stream>>>(ei, cursor, src_sorted, E, Nn);

  int gx64 = (Nn + 63) / 64;           // 157 row-panels for v3
  int PX3 = (gx64 + 7) / 8;            // 20
  int nblk3 = 8 * PX3 * 4;             // 640 blocks
  int gx128 = (Nn + 127) / 128;        // 79 (layer 3)
  int ga = (Nn + 3) / 4;               // control grid
  int gs = ga * 8;                     // sliced grid (8 head-slices)

  // layer 1: 256 -> 8x64 concat (split-A, alpha fused); agg8 TEST (XCD-sliced)
  gemm_v3<true><<<nblk3, 256, 0, stream>>>(xsh, xsl, W1th, Hb16,
                                           asrc1, adst1, als, ald, Nn, 256, 512, PX3);
  agg8s_kernel<<<gs, 256, 0, stream>>>(Hb16, als, ald, b1, row_ptr, src_sorted, Ahb, Nn);
  // layer 2: 512 -> 8x64 concat (1-pass A); agg8 CONTROL (r10 body)
  gemm_v3<false><<<nblk3, 256, 0, stream>>>(Ahb, nullptr, W2th, Hb16,
                                            asrc2, adst2, als, ald, Nn, 512, 512, PX3);
  agg8_kernel<<<ga, 256, 0, stream>>>(Hb16, als, ald, b2, row_ptr, src_sorted, Ahb, Nn);
  // layer 3: 512 -> 64, 1 head (1-pass A, fp32 out, alpha fused)
  gemm_v2<<<gx128, 256, 0, stream>>>(Ahb, W3th, Hb3,
                                     asrc3, adst3, als, ald, Nn, 512, 64);
  // aggregate + classifier + log_softmax
  agg1cls_kernel<<<ga, 256, 0, stream>>>(Hb3, als, ald, b3, row_ptr, src_sorted,
                                         linW, linb, out, Nn);
}

// Round 14
// 202.772 us; speedup vs baseline: 1.1471x; 1.1471x over previous
//
#include <hip/hip_runtime.h>
#include <cmath>

#define NEG 0.2f

typedef __bf16 bf16x8 __attribute__((ext_vector_type(8)));
typedef float  f32x4  __attribute__((ext_vector_type(4)));

__device__ __forceinline__ void async16(const __bf16* g, __bf16* l) {
  __builtin_amdgcn_global_load_lds(
      (const __attribute__((address_space(1))) void*)g,
      (__attribute__((address_space(3))) void*)l, 16, 0, 0);
}
__device__ __forceinline__ f32x4 mfma16(bf16x8 a, bf16x8 b, f32x4 c) {
  return __builtin_amdgcn_mfma_f32_16x16x32_bf16(a, b, c, 0, 0, 0);
}

// ---------------- CSR build ----------------
__global__ void count_kernel(const int* __restrict__ ei, int* __restrict__ counts, int E, int Nn) {
  int e = blockIdx.x * blockDim.x + threadIdx.x;
  if (e >= E + Nn) return;
  int d = (e < E) ? ei[E + e] : (e - E);
  atomicAdd(&counts[d], 1);
}

__global__ __launch_bounds__(1024) void scan_kernel(const int* __restrict__ counts,
                                                    int* __restrict__ row_ptr,
                                                    int* __restrict__ cursor,
                                                    int n, int total) {
  __shared__ int sums[1024];
  int t = threadIdx.x;
  int per = (n + 1023) >> 10;
  int base = t * per;
  int s = 0;
  for (int i = 0; i < per; ++i) { int idx = base + i; if (idx < n) s += counts[idx]; }
  sums[t] = s;
  __syncthreads();
  for (int st = 1; st < 1024; st <<= 1) {
    int v = (t >= st) ? sums[t - st] : 0;
    __syncthreads();
    sums[t] += v;
    __syncthreads();
  }
  int off = (t == 0) ? 0 : sums[t - 1];
  for (int i = 0; i < per; ++i) {
    int idx = base + i;
    if (idx < n) { row_ptr[idx] = off; cursor[idx] = off; off += counts[idx]; }
  }
  if (t == 0) row_ptr[n] = total;
}

__global__ void scatter_kernel(const int* __restrict__ ei, int* __restrict__ cursor,
                               int* __restrict__ src_sorted, int E, int Nn) {
  int e = blockIdx.x * blockDim.x + threadIdx.x;
  if (e >= E + Nn) return;
  int s, d;
  if (e < E) { s = ei[e]; d = ei[E + e]; } else { s = e - E; d = e - E; }
  int pos = atomicAdd(&cursor[d], 1);
  src_sorted[pos] = s;
}

// ------- fused prep: zero counts, split x, transpose W1/W2/W3 (high only) ----
__global__ void prep_kernel(const float* __restrict__ x, __bf16* __restrict__ xsh,
                            __bf16* __restrict__ xsl,
                            const float* __restrict__ W1, __bf16* __restrict__ W1th,
                            const float* __restrict__ W2, __bf16* __restrict__ W2th,
                            const float* __restrict__ W3, __bf16* __restrict__ W3th,
                            int* __restrict__ counts, int Nn) {
  int i = blockIdx.x * blockDim.x + threadIdx.x;
  if (i < Nn) { counts[i] = 0; return; }
  i -= Nn;
  int nx = Nn * 256;
  if (i < nx) {
    float v = x[i];
    __bf16 h = (__bf16)v;
    xsh[i] = h;
    xsl[i] = (__bf16)(v - (float)h);
    return;
  }
  i -= nx;
  if (i < 256 * 512) {
    int k = i / 512, c = i % 512;
    W1th[(size_t)c * 256 + k] = (__bf16)W1[i];
    return;
  }
  i -= 256 * 512;
  if (i < 512 * 512) {
    int k = i / 512, c = i % 512;
    W2th[(size_t)c * 512 + k] = (__bf16)W2[i];
    return;
  }
  i -= 512 * 512;
  if (i < 512 * 64) {
    int k = i / 64, c = i % 64;
    W3th[(size_t)c * 512 + k] = (__bf16)W3[i];
    return;
  }
}

// ------- bf16 MFMA GEMM v3: BM=64, BN=128 (two heads), fused alpha -----------
template <bool ASPLIT>
__global__ __launch_bounds__(256, 4) void gemm_v3(
    const __bf16* __restrict__ Ah, const __bf16* __restrict__ Al,
    const __bf16* __restrict__ Bth,
    __bf16* __restrict__ Cb,
    const float* __restrict__ asrc, const float* __restrict__ adst,
    float* __restrict__ als, float* __restrict__ ald,
    int M, int K, int Nc, int PX) {
  __shared__ __bf16 sAh[64 * 64], sBh[128 * 64];
  __shared__ __bf16 sAl[ASPLIT ? 64 * 64 : 64];

  int p = blockIdx.x;          // XCD = p%8 (round-robin dispatch)
  int c = p & 7, j = p >> 3;   // row-panels c*PX.. pinned to XCD c
  int x = c * PX + (j >> 2);
  int y = j & 3;
  int rowBase = x * 64, colBase = y * 128;
  if (rowBase >= M) return;

  int tid = threadIdx.x;
  int lane = tid & 63, wave = tid >> 6;
  int r16 = lane & 15, koct = lane >> 4, msk = r16 & 7;

  int fa0 = tid, fa1 = 256 + tid;
  int ar0 = fa0 >> 3, ar1 = fa1 >> 3;
  int as0 = (fa0 & 7) ^ (ar0 & 7);
  int as1 = (fa1 & 7) ^ (ar1 & 7);
  size_t aoff0 = (size_t)min(rowBase + ar0, M - 1) * K + as0 * 8;
  size_t aoff1 = (size_t)min(rowBase + ar1, M - 1) * K + as1 * 8;
  size_t boff[4];
#pragma unroll
  for (int r = 0; r < 4; ++r) {
    int f = r * 256 + tid;
    int col = f >> 3;
    int s = (f & 7) ^ (col & 7);
    boff[r] = (size_t)(colBase + col) * K + s * 8;
  }
  int lb0 = (wave * 64) * 8;
  int lb1 = ((256 + wave * 64)) * 8;
  int lb2 = ((512 + wave * 64)) * 8;
  int lb3 = ((768 + wave * 64)) * 8;

  int arow = wave * 16 + r16;
  f32x4 acc[8] = {};

  for (int k0 = 0; k0 < K; k0 += 64) {
    __syncthreads();
    async16(Ah + aoff0 + k0, sAh + lb0);
    async16(Ah + aoff1 + k0, sAh + lb1);
    if (ASPLIT) {
      async16(Al + aoff0 + k0, sAl + lb0);
      async16(Al + aoff1 + k0, sAl + lb1);
    }
    async16(Bth + boff[0] + k0, sBh + lb0);
    async16(Bth + boff[1] + k0, sBh + lb1);
    async16(Bth + boff[2] + k0, sBh + lb2);
    async16(Bth + boff[3] + k0, sBh + lb3);
    __syncthreads();

#pragma unroll
    for (int kk = 0; kk < 2; ++kk) {
      int ks = ((kk * 4 + koct) ^ msk) * 8;
      bf16x8 ah = *reinterpret_cast<const bf16x8*>(sAh + arow * 64 + ks);
      bf16x8 al;
      if (ASPLIT) al = *reinterpret_cast<const bf16x8*>(sAl + arow * 64 + ks);
      bf16x8 bh[8];
#pragma unroll
      for (int fn = 0; fn < 8; ++fn)
        bh[fn] = *reinterpret_cast<const bf16x8*>(sBh + (fn * 16 + r16) * 64 + ks);
#pragma unroll
      for (int fn = 0; fn < 8; ++fn) {
        acc[fn] = mfma16(ah, bh[fn], acc[fn]);
        if (ASPLIT) acc[fn] = mfma16(al, bh[fn], acc[fn]);
      }
    }
  }

  float asv[8], adv[8];
#pragma unroll
  for (int fn = 0; fn < 8; ++fn) {
    int ai = (y * 2 + (fn >> 2)) * 64 + (fn & 3) * 16 + r16;
    asv[fn] = asrc[ai];
    adv[fn] = adst[ai];
  }
#pragma unroll
  for (int r = 0; r < 4; ++r) {
    int row = rowBase + wave * 16 + koct * 4 + r;
    float psA = 0.f, pdA = 0.f, psB = 0.f, pdB = 0.f;
#pragma unroll
    for (int fn = 0; fn < 8; ++fn) {
      float v = acc[fn][r];
      if (row < M) Cb[(size_t)row * Nc + colBase + fn * 16 + r16] = (__bf16)v;
      if (fn < 4) { psA = fmaf(v, asv[fn], psA); pdA = fmaf(v, adv[fn], pdA); }
      else        { psB = fmaf(v, asv[fn], psB); pdB = fmaf(v, adv[fn], pdB); }
    }
#pragma unroll
    for (int sft = 1; sft < 16; sft <<= 1) {
      psA += __shfl_xor(psA, sft); pdA += __shfl_xor(pdA, sft);
      psB += __shfl_xor(psB, sft); pdB += __shfl_xor(pdB, sft);
    }
    if (r16 == 0 && row < M) {
      als[(size_t)row * 8 + y * 2 + 0] = psA;
      ald[(size_t)row * 8 + y * 2 + 0] = pdA;
      als[(size_t)row * 8 + y * 2 + 1] = psB;
      ald[(size_t)row * 8 + y * 2 + 1] = pdB;
    }
  }
}

// ------- bf16 MFMA GEMM v2: BM=128, BN=64, BK=64, 1-pass A — layer 3 ---------
__global__ __launch_bounds__(256, 4) void gemm_v2(
    const __bf16* __restrict__ Ah,
    const __bf16* __restrict__ Bth,
    float* __restrict__ Cf,
    const float* __restrict__ asrc, const float* __restrict__ adst,
    float* __restrict__ als, float* __restrict__ ald,
    int M, int K, int Nc) {
  __shared__ __bf16 sAh[128 * 64], sBh[64 * 64];

  int x = blockIdx.x;
  int rowBase = x * 128, colBase = 0;
  if (rowBase >= M) return;

  int tid = threadIdx.x;
  int lane = tid & 63, wave = tid >> 6;
  int r16 = lane & 15, koct = lane >> 4, msk = r16 & 7;

  f32x4 acc[2][4] = {};

  for (int k0 = 0; k0 < K; k0 += 64) {
    __syncthreads();
#pragma unroll
    for (int r = 0; r < 4; ++r) {
      int flat = r * 256 + tid;
      int row = flat >> 3;
      int grow = rowBase + row;
      if (grow >= M) grow = M - 1;
      int s = (flat & 7) ^ (row & 7);
      size_t go = (size_t)grow * K + k0 + s * 8;
      int lb = (r * 256 + wave * 64) * 8;
      async16(Ah + go, sAh + lb);
    }
#pragma unroll
    for (int r = 0; r < 2; ++r) {
      int flat = r * 256 + tid;
      int col = flat >> 3;
      int s = (flat & 7) ^ (col & 7);
      size_t go = (size_t)(colBase + col) * K + k0 + s * 8;
      int lb = (r * 256 + wave * 64) * 8;
      async16(Bth + go, sBh + lb);
    }
    __syncthreads();

#pragma unroll
    for (int kk = 0; kk < 2; ++kk) {
      bf16x8 ah[2], bh[4];
#pragma unroll
      for (int fm = 0; fm < 2; ++fm) {
        int off = (wave * 32 + fm * 16 + r16) * 64 + (((kk * 4 + koct) ^ msk) * 8);
        ah[fm] = *reinterpret_cast<const bf16x8*>(sAh + off);
      }
#pragma unroll
      for (int fn = 0; fn < 4; ++fn) {
        int off = (fn * 16 + r16) * 64 + (((kk * 4 + koct) ^ msk) * 8);
        bh[fn] = *reinterpret_cast<const bf16x8*>(sBh + off);
      }
#pragma unroll
      for (int fm = 0; fm < 2; ++fm)
#pragma unroll
        for (int fn = 0; fn < 4; ++fn)
          acc[fm][fn] = mfma16(ah[fm], bh[fn], acc[fm][fn]);
    }
  }

  float asv[4], adv[4];
#pragma unroll
  for (int fn = 0; fn < 4; ++fn) {
    asv[fn] = asrc[fn * 16 + r16];
    adv[fn] = adst[fn * 16 + r16];
  }
#pragma unroll
  for (int fm = 0; fm < 2; ++fm)
#pragma unroll
    for (int r = 0; r < 4; ++r) {
      int row = rowBase + wave * 32 + fm * 16 + koct * 4 + r;
      float ps = 0.f, pd = 0.f;
#pragma unroll
      for (int fn = 0; fn < 4; ++fn) {
        float v = acc[fm][fn][r];
        ps = fmaf(v, asv[fn], ps);
        pd = fmaf(v, adv[fn], pd);
        if (row < M) Cf[(size_t)row * Nc + fn * 16 + r16] = v;
      }
#pragma unroll
      for (int sft = 1; sft < 16; sft <<= 1) {
        ps += __shfl_xor(ps, sft);
        pd += __shfl_xor(pd, sft);
      }
      if (r16 == 0 && row < M) {
        als[row] = ps;
        ald[row] = pd;
      }
    }
}

// ------- TEST: slice-local aggregate keeping r10 per-lane structure ----------
// 4 column-slices of 128; wave = 4 nodes x 16 col-groups. Each lane runs the
// exact r10 loop (8 edges/chunk, 8 gathers, own mrun) for its node, touching
// only its 128-col slice. slice = (blockIdx&7)>>1 -> XCD-pair-local L2 set
// (slice 2.56MB + src_sorted 1.3MB + alpha 0.6MB ~= 4MB). Numerics == r10.
__global__ __launch_bounds__(256) void agg8v4_kernel(const __bf16* __restrict__ Hb, // [N,512]
                                                     const float* __restrict__ als,
                                                     const float* __restrict__ ald,
                                                     const float* __restrict__ bias,
                                                     const int* __restrict__ row_ptr,
                                                     const int* __restrict__ src_sorted,
                                                     __bf16* __restrict__ Oh,      // [N,512]
                                                     int Nn) {
  int c8 = blockIdx.x & 7;     // XCD id (round-robin dispatch)
  int sl = c8 >> 1;            // column-slice 0..3 (2 XCDs per slice)
  int chunk = (blockIdx.x >> 3) * 2 + (c8 & 1);
  int lane = threadIdx.x & 63, wave = threadIdx.x >> 6;
  int sub = lane >> 4;         // node sub-index within wave (0..3)
  int cg = lane & 15;          // col-group within 128-col slice
  int n = chunk * 16 + wave * 4 + sub;
  bool alive = (n < Nn);
  if (!alive) n = Nn - 1;
  int head = sl * 2 + (cg >> 3);
  int colb = head * 64 + (cg & 7) * 8;  // == sl*128 + cg*8

  int start = row_ptr[n], deg = row_ptr[n + 1] - start;
  float aldn = ald[n * 8 + head];
  // wave-uniform loop bound: max deg among the wave's 4 nodes
  int dm = deg;
  dm = max(dm, __shfl_xor(dm, 16));
  dm = max(dm, __shfl_xor(dm, 32));

  float acc[8] = {};
  float ssum = 0.f;
  float mrun = 0.f;
  const __bf16* hcol = Hb + colb;
  for (int e0 = 0; e0 < dm; e0 += 8) {
    int idx[8];
    float lv[8];
    bf16x8 v[8];
#pragma unroll
    for (int i = 0; i < 8; ++i) {
      int e = e0 + i;
      if (e > deg - 1) e = deg - 1;
      idx[i] = src_sorted[start + e];
    }
#pragma unroll
    for (int i = 0; i < 8; ++i) lv[i] = als[idx[i] * 8 + head];
#pragma unroll
    for (int i = 0; i < 8; ++i)
      v[i] = *reinterpret_cast<const bf16x8*>(hcol + (size_t)idx[i] * 512);
    float lm = -INFINITY;
#pragma unroll
    for (int i = 0; i < 8; ++i) {
      float l = lv[i] + aldn;
      l = l > 0.f ? l : NEG * l;
      lv[i] = l;
      lm = fmaxf(lm, l);
    }
    if (__builtin_expect(lm > mrun + 24.f, 0)) {
      float sc = __expf(mrun - lm);
      ssum *= sc;
#pragma unroll
      for (int j = 0; j < 8; ++j) acc[j] *= sc;
      mrun = lm;
    }
#pragma unroll
    for (int i = 0; i < 8; ++i) {
      float w = (e0 + i < deg) ? __expf(lv[i] - mrun) : 0.f;
      ssum += w;
#pragma unroll
      for (int j = 0; j < 8; ++j) acc[j] = fmaf(w, (float)v[i][j], acc[j]);
    }
  }

  if (alive) {
    float inv = 1.f / (ssum + 1e-16f);
    bf16x8 vh;
#pragma unroll
    for (int j = 0; j < 8; ++j) {
      float v = acc[j] * inv + bias[colb + j];
      v = v > 0.f ? v : expm1f(v);
      vh[j] = (__bf16)v;
    }
    *reinterpret_cast<bf16x8*>(Oh + (size_t)n * 512 + colb) = vh;
  }
}

// ------- CONTROL: r10 fused aggregate, 8 heads: one WAVE per node ------------
__global__ __launch_bounds__(256) void agg8_kernel(const __bf16* __restrict__ Hb,  // [N,512]
                                                   const float* __restrict__ als,  // [N,8]
                                                   const float* __restrict__ ald,  // [N,8]
                                                   const float* __restrict__ bias, // [512]
                                                   const int* __restrict__ row_ptr,
                                                   const int* __restrict__ src_sorted,
                                                   __bf16* __restrict__ Oh,        // [N,512]
                                                   int Nn) {
  int n = (blockIdx.x * 256 + threadIdx.x) >> 6;
  if (n >= Nn) return;
  int lane = threadIdx.x & 63;
  int hh = lane >> 3;
  int start = row_ptr[n], deg = row_ptr[n + 1] - start;
  float aldn = ald[n * 8 + hh];

  float acc[8] = {};
  float ssum = 0.f;
  float mrun = 0.f;
  const __bf16* hcol = Hb + lane * 8;
  for (int e0 = 0; e0 < deg; e0 += 8) {
    int idx[8];
    float lv[8];
    bf16x8 v[8];
#pragma unroll
    for (int i = 0; i < 8; ++i) {
      int e = e0 + i;
      if (e > deg - 1) e = deg - 1;
      idx[i] = src_sorted[start + e];
    }
#pragma unroll
    for (int i = 0; i < 8; ++i) lv[i] = als[idx[i] * 8 + hh];
#pragma unroll
    for (int i = 0; i < 8; ++i)
      v[i] = *reinterpret_cast<const bf16x8*>(hcol + (size_t)idx[i] * 512);
    float lm = -INFINITY;
#pragma unroll
    for (int i = 0; i < 8; ++i) {
      float l = lv[i] + aldn;
      l = l > 0.f ? l : NEG * l;
      lv[i] = l;
      lm = fmaxf(lm, l);
    }
    if (__builtin_expect(lm > mrun + 24.f, 0)) {
      float sc = __expf(mrun - lm);
      ssum *= sc;
#pragma unroll
      for (int j = 0; j < 8; ++j) acc[j] *= sc;
      mrun = lm;
    }
#pragma unroll
    for (int i = 0; i < 8; ++i) {
      float w = (e0 + i < deg) ? __expf(lv[i] - mrun) : 0.f;
      ssum += w;
#pragma unroll
      for (int j = 0; j < 8; ++j) acc[j] = fmaf(w, (float)v[i][j], acc[j]);
    }
  }

  float inv = 1.f / (ssum + 1e-16f);
  bf16x8 vh;
#pragma unroll
  for (int j = 0; j < 8; ++j) {
    float v = acc[j] * inv + bias[lane * 8 + j];
    v = v > 0.f ? v : expm1f(v);
    vh[j] = (__bf16)v;
  }
  *reinterpret_cast<bf16x8*>(Oh + (size_t)n * 512 + lane * 8) = vh;
}

// ------- fused aggregate (1 head, one-pass) + classifier + log_softmax ------
__global__ __launch_bounds__(256) void agg1cls_kernel(const float* __restrict__ Hf, // [N,64]
                                                      const float* __restrict__ als,
                                                      const float* __restrict__ ald,
                                                      const float* __restrict__ bias,
                                                      const int* __restrict__ row_ptr,
                                                      const int* __restrict__ src_sorted,
                                                      const float* __restrict__ lw,  // [64,2]
                                                      const float* __restrict__ lb,  // [2]
                                                      float* __restrict__ out,       // [N,2]
                                                      int Nn) {
  int n = (blockIdx.x * 256 + threadIdx.x) >> 6;
  if (n >= Nn) return;
  int lane = threadIdx.x & 63;
  int start = row_ptr[n], deg = row_ptr[n + 1] - start;
  float aldn = ald[n];

  float acc = 0.f, ssum = 0.f, mrun = 0.f;
  for (int e0 = 0; e0 < deg; e0 += 8) {
    int idx[8];
    float lv[8], hv[8];
#pragma unroll
    for (int i = 0; i < 8; ++i) {
      int e = e0 + i;
      if (e > deg - 1) e = deg - 1;
      idx[i] = src_sorted[start + e];
    }
#pragma unroll
    for (int i = 0; i < 8; ++i) lv[i] = als[idx[i]];
#pragma unroll
    for (int i = 0; i < 8; ++i) hv[i] = Hf[(size_t)idx[i] * 64 + lane];
    float lm = -INFINITY;
#pragma unroll
    for (int i = 0; i < 8; ++i) {
      float l = lv[i] + aldn;
      l = l > 0.f ? l : NEG * l;
      lv[i] = l;
      lm = fmaxf(lm, l);
    }
    if (__builtin_expect(lm > mrun + 24.f, 0)) {
      float sc = __expf(mrun - lm);
      ssum *= sc;
      acc *= sc;
      mrun = lm;
    }
#pragma unroll
    for (int i = 0; i < 8; ++i) {
      float w = (e0 + i < deg) ? __expf(lv[i] - mrun) : 0.f;
      ssum += w;
      acc = fmaf(w, hv[i], acc);
    }
  }
  float o = acc / (ssum + 1e-16f) + bias[lane];

  float p0 = o * lw[lane * 2 + 0];
  float p1 = o * lw[lane * 2 + 1];
  for (int s = 32; s; s >>= 1) {
    p0 += __shfl_xor(p0, s);
    p1 += __shfl_xor(p1, s);
  }
  if (lane == 0) {
    p0 += lb[0];
    p1 += lb[1];
    float mx = fmaxf(p0, p1);
    float lse = mx + logf(expf(p0 - mx) + expf(p1 - mx));
    out[n * 2 + 0] = p0 - lse;
    out[n * 2 + 1] = p1 - lse;
  }
}

extern "C" void kernel_launch(void* const* d_in, const int* in_sizes, int n_in,
                              void* d_out, int out_size, void* d_ws, size_t ws_size,
                              hipStream_t stream) {
  (void)n_in; (void)out_size; (void)ws_size;
  const float* x     = (const float*)d_in[0];
  const int*   ei    = (const int*)d_in[1];
  const float* W1    = (const float*)d_in[2];
  const float* asrc1 = (const float*)d_in[3];
  const float* adst1 = (const float*)d_in[4];
  const float* b1    = (const float*)d_in[5];
  const float* W2    = (const float*)d_in[6];
  const float* asrc2 = (const float*)d_in[7];
  const float* adst2 = (const float*)d_in[8];
  const float* b2    = (const float*)d_in[9];
  const float* W3    = (const float*)d_in[10];
  const float* asrc3 = (const float*)d_in[11];
  const float* adst3 = (const float*)d_in[12];
  const float* b3    = (const float*)d_in[13];
  const float* linW  = (const float*)d_in[14];
  const float* linb  = (const float*)d_in[15];
  float* out = (float*)d_out;

  int Nn = in_sizes[0] / 256;
  int E  = in_sizes[1] / 2;
  int E2 = E + Nn;

  char* w = (char*)d_ws;
  auto carve = [&](size_t bytes) {
    char* p = w;
    w += (bytes + 63) & ~(size_t)63;
    return p;
  };
  __bf16* xsh  = (__bf16*)carve((size_t)Nn * 256 * 2);
  __bf16* xsl  = (__bf16*)carve((size_t)Nn * 256 * 2);
  __bf16* Ahb  = (__bf16*)carve((size_t)Nn * 512 * 2);
  __bf16* Hb16 = (__bf16*)carve((size_t)Nn * 512 * 2);
  float*  Hb3  = (float*)carve((size_t)Nn * 64 * 4);
  float*  als  = (float*)carve((size_t)Nn * 8 * 4);
  float*  ald  = (float*)carve((size_t)Nn * 8 * 4);
  __bf16* W1th = (__bf16*)carve(256 * 512 * 2);
  __bf16* W2th = (__bf16*)carve(512 * 512 * 2);
  __bf16* W3th = (__bf16*)carve(512 * 64 * 2);
  int* counts     = (int*)carve((size_t)Nn * 4);
  int* cursor     = (int*)carve((size_t)Nn * 4);
  int* row_ptr    = (int*)carve(((size_t)Nn + 1) * 4);
  int* src_sorted = (int*)carve((size_t)E2 * 4);

  int prep_total = Nn + Nn * 256 + 256 * 512 + 512 * 512 + 512 * 64;
  prep_kernel<<<(prep_total + 255) / 256, 256, 0, stream>>>(
      x, xsh, xsl, W1, W1th, W2, W2th, W3, W3th, counts, Nn);
  count_kernel<<<(E2 + 255) / 256, 256, 0, stream>>>(ei, counts, E, Nn);
  scan_kernel<<<1, 1024, 0, stream>>>(counts, row_ptr, cursor, Nn, E2);
  scatter_kernel<<<(E2 + 255) / 256, 256, 0, stream>>>(ei, cursor, src_sorted, E, Nn);

  int gx64 = (Nn + 63) / 64;           // 157 row-panels for v3
  int PX3 = (gx64 + 7) / 8;            // 20
  int nblk3 = 8 * PX3 * 4;             // 640 blocks
  int gx128 = (Nn + 127) / 128;        // 79 (layer 3)
  int ga = (Nn + 3) / 4;               // control grid
  int gv4 = ((Nn + 31) / 32) * 8;      // v4 grid: 16 nodes/block, 2 chunks/XCD-pair step

  // layer 1: 256 -> 8x64 concat (split-A, alpha fused); agg8 TEST (v4 slice-local)
  gemm_v3<true><<<nblk3, 256, 0, stream>>>(xsh, xsl, W1th, Hb16,
                                           asrc1, adst1, als, ald, Nn, 256, 512, PX3);
  agg8v4_kernel<<<gv4, 256, 0, stream>>>(Hb16, als, ald, b1, row_ptr, src_sorted, Ahb, Nn);
  // layer 2: 512 -> 8x64 concat (1-pass A); agg8 CONTROL (r10 body)
  gemm_v3<false><<<nblk3, 256, 0, stream>>>(Ahb, nullptr, W2th, Hb16,
                                            asrc2, adst2, als, ald, Nn, 512, 512, PX3);
  agg8_kernel<<<ga, 256, 0, stream>>>(Hb16, als, ald, b2, row_ptr, src_sorted, Ahb, Nn);
  // layer 3: 512 -> 64, 1 head (1-pass A, fp32 out, alpha fused)
  gemm_v2<<<gx128, 256, 0, stream>>>(Ahb, W3th, Hb3,
                                     asrc3, adst3, als, ald, Nn, 512, 64);
  // aggregate + classifier + log_softmax
  agg1cls_kernel<<<ga, 256, 0, stream>>>(Hb3, als, ald, b3, row_ptr, src_sorted,
                                         linW, linb, out, Nn);
}

// Round 15
// 198.740 us; speedup vs baseline: 1.1704x; 1.0203x over previous
//
#include <hip/hip_runtime.h>
#include <cmath>

#define NEG 0.2f

typedef __bf16 bf16x8 __attribute__((ext_vector_type(8)));
typedef float  f32x4  __attribute__((ext_vector_type(4)));

__device__ __forceinline__ void async16(const __bf16* g, __bf16* l) {
  __builtin_amdgcn_global_load_lds(
      (const __attribute__((address_space(1))) void*)g,
      (__attribute__((address_space(3))) void*)l, 16, 0, 0);
}
__device__ __forceinline__ f32x4 mfma16(bf16x8 a, bf16x8 b, f32x4 c) {
  return __builtin_amdgcn_mfma_f32_16x16x32_bf16(a, b, c, 0, 0, 0);
}

// ---------------- CSR build ----------------
__global__ void count_kernel(const int* __restrict__ ei, int* __restrict__ counts, int E, int Nn) {
  int e = blockIdx.x * blockDim.x + threadIdx.x;
  if (e >= E + Nn) return;
  int d = (e < E) ? ei[E + e] : (e - E);
  atomicAdd(&counts[d], 1);
}

__global__ __launch_bounds__(1024) void scan_kernel(const int* __restrict__ counts,
                                                    int* __restrict__ row_ptr,
                                                    int* __restrict__ cursor,
                                                    int n, int total) {
  __shared__ int sums[1024];
  int t = threadIdx.x;
  int per = (n + 1023) >> 10;
  int base = t * per;
  int s = 0;
  for (int i = 0; i < per; ++i) { int idx = base + i; if (idx < n) s += counts[idx]; }
  sums[t] = s;
  __syncthreads();
  for (int st = 1; st < 1024; st <<= 1) {
    int v = (t >= st) ? sums[t - st] : 0;
    __syncthreads();
    sums[t] += v;
    __syncthreads();
  }
  int off = (t == 0) ? 0 : sums[t - 1];
  for (int i = 0; i < per; ++i) {
    int idx = base + i;
    if (idx < n) { row_ptr[idx] = off; cursor[idx] = off; off += counts[idx]; }
  }
  if (t == 0) row_ptr[n] = total;
}

__global__ void scatter_kernel(const int* __restrict__ ei, int* __restrict__ cursor,
                               int* __restrict__ src_sorted, int E, int Nn) {
  int e = blockIdx.x * blockDim.x + threadIdx.x;
  if (e >= E + Nn) return;
  int s, d;
  if (e < E) { s = ei[e]; d = ei[E + e]; } else { s = e - E; d = e - E; }
  int pos = atomicAdd(&cursor[d], 1);
  src_sorted[pos] = s;
}

// ------- fused prep: zero counts, split x, transpose W1/W2/W3 (high only) ----
__global__ void prep_kernel(const float* __restrict__ x, __bf16* __restrict__ xsh,
                            __bf16* __restrict__ xsl,
                            const float* __restrict__ W1, __bf16* __restrict__ W1th,
                            const float* __restrict__ W2, __bf16* __restrict__ W2th,
                            const float* __restrict__ W3, __bf16* __restrict__ W3th,
                            int* __restrict__ counts, int Nn) {
  int i = blockIdx.x * blockDim.x + threadIdx.x;
  if (i < Nn) { counts[i] = 0; return; }
  i -= Nn;
  int nx = Nn * 256;
  if (i < nx) {
    float v = x[i];
    __bf16 h = (__bf16)v;
    xsh[i] = h;
    xsl[i] = (__bf16)(v - (float)h);
    return;
  }
  i -= nx;
  if (i < 256 * 512) {
    int k = i / 512, c = i % 512;
    W1th[(size_t)c * 256 + k] = (__bf16)W1[i];
    return;
  }
  i -= 256 * 512;
  if (i < 512 * 512) {
    int k = i / 512, c = i % 512;
    W2th[(size_t)c * 512 + k] = (__bf16)W2[i];
    return;
  }
  i -= 512 * 512;
  if (i < 512 * 64) {
    int k = i / 64, c = i % 64;
    W3th[(size_t)c * 512 + k] = (__bf16)W3[i];
    return;
  }
}

// ------- bf16 MFMA GEMM v3: BM=64, BN=128 (two heads), fused alpha -----------
template <bool ASPLIT>
__global__ __launch_bounds__(256, 4) void gemm_v3(
    const __bf16* __restrict__ Ah, const __bf16* __restrict__ Al,
    const __bf16* __restrict__ Bth,
    __bf16* __restrict__ Cb,
    const float* __restrict__ asrc, const float* __restrict__ adst,
    float* __restrict__ als, float* __restrict__ ald,
    int M, int K, int Nc, int PX) {
  __shared__ __bf16 sAh[64 * 64], sBh[128 * 64];
  __shared__ __bf16 sAl[ASPLIT ? 64 * 64 : 64];

  int p = blockIdx.x;          // XCD = p%8 (round-robin dispatch)
  int c = p & 7, j = p >> 3;   // row-panels c*PX.. pinned to XCD c
  int x = c * PX + (j >> 2);
  int y = j & 3;
  int rowBase = x * 64, colBase = y * 128;
  if (rowBase >= M) return;

  int tid = threadIdx.x;
  int lane = tid & 63, wave = tid >> 6;
  int r16 = lane & 15, koct = lane >> 4, msk = r16 & 7;

  int fa0 = tid, fa1 = 256 + tid;
  int ar0 = fa0 >> 3, ar1 = fa1 >> 3;
  int as0 = (fa0 & 7) ^ (ar0 & 7);
  int as1 = (fa1 & 7) ^ (ar1 & 7);
  size_t aoff0 = (size_t)min(rowBase + ar0, M - 1) * K + as0 * 8;
  size_t aoff1 = (size_t)min(rowBase + ar1, M - 1) * K + as1 * 8;
  size_t boff[4];
#pragma unroll
  for (int r = 0; r < 4; ++r) {
    int f = r * 256 + tid;
    int col = f >> 3;
    int s = (f & 7) ^ (col & 7);
    boff[r] = (size_t)(colBase + col) * K + s * 8;
  }
  int lb0 = (wave * 64) * 8;
  int lb1 = ((256 + wave * 64)) * 8;
  int lb2 = ((512 + wave * 64)) * 8;
  int lb3 = ((768 + wave * 64)) * 8;

  int arow = wave * 16 + r16;
  f32x4 acc[8] = {};

  for (int k0 = 0; k0 < K; k0 += 64) {
    __syncthreads();
    async16(Ah + aoff0 + k0, sAh + lb0);
    async16(Ah + aoff1 + k0, sAh + lb1);
    if (ASPLIT) {
      async16(Al + aoff0 + k0, sAl + lb0);
      async16(Al + aoff1 + k0, sAl + lb1);
    }
    async16(Bth + boff[0] + k0, sBh + lb0);
    async16(Bth + boff[1] + k0, sBh + lb1);
    async16(Bth + boff[2] + k0, sBh + lb2);
    async16(Bth + boff[3] + k0, sBh + lb3);
    __syncthreads();

#pragma unroll
    for (int kk = 0; kk < 2; ++kk) {
      int ks = ((kk * 4 + koct) ^ msk) * 8;
      bf16x8 ah = *reinterpret_cast<const bf16x8*>(sAh + arow * 64 + ks);
      bf16x8 al;
      if (ASPLIT) al = *reinterpret_cast<const bf16x8*>(sAl + arow * 64 + ks);
      bf16x8 bh[8];
#pragma unroll
      for (int fn = 0; fn < 8; ++fn)
        bh[fn] = *reinterpret_cast<const bf16x8*>(sBh + (fn * 16 + r16) * 64 + ks);
#pragma unroll
      for (int fn = 0; fn < 8; ++fn) {
        acc[fn] = mfma16(ah, bh[fn], acc[fn]);
        if (ASPLIT) acc[fn] = mfma16(al, bh[fn], acc[fn]);
      }
    }
  }

  float asv[8], adv[8];
#pragma unroll
  for (int fn = 0; fn < 8; ++fn) {
    int ai = (y * 2 + (fn >> 2)) * 64 + (fn & 3) * 16 + r16;
    asv[fn] = asrc[ai];
    adv[fn] = adst[ai];
  }
#pragma unroll
  for (int r = 0; r < 4; ++r) {
    int row = rowBase + wave * 16 + koct * 4 + r;
    float psA = 0.f, pdA = 0.f, psB = 0.f, pdB = 0.f;
#pragma unroll
    for (int fn = 0; fn < 8; ++fn) {
      float v = acc[fn][r];
      if (row < M) Cb[(size_t)row * Nc + colBase + fn * 16 + r16] = (__bf16)v;
      if (fn < 4) { psA = fmaf(v, asv[fn], psA); pdA = fmaf(v, adv[fn], pdA); }
      else        { psB = fmaf(v, asv[fn], psB); pdB = fmaf(v, adv[fn], pdB); }
    }
#pragma unroll
    for (int sft = 1; sft < 16; sft <<= 1) {
      psA += __shfl_xor(psA, sft); pdA += __shfl_xor(pdA, sft);
      psB += __shfl_xor(psB, sft); pdB += __shfl_xor(pdB, sft);
    }
    if (r16 == 0 && row < M) {
      als[(size_t)row * 8 + y * 2 + 0] = psA;
      ald[(size_t)row * 8 + y * 2 + 0] = pdA;
      als[(size_t)row * 8 + y * 2 + 1] = psB;
      ald[(size_t)row * 8 + y * 2 + 1] = pdB;
    }
  }
}

// ------- bf16 MFMA GEMM v2: BM=128, BN=64, BK=64, 1-pass A — layer 3 ---------
__global__ __launch_bounds__(256, 4) void gemm_v2(
    const __bf16* __restrict__ Ah,
    const __bf16* __restrict__ Bth,
    float* __restrict__ Cf,
    const float* __restrict__ asrc, const float* __restrict__ adst,
    float* __restrict__ als, float* __restrict__ ald,
    int M, int K, int Nc) {
  __shared__ __bf16 sAh[128 * 64], sBh[64 * 64];

  int x = blockIdx.x;
  int rowBase = x * 128, colBase = 0;
  if (rowBase >= M) return;

  int tid = threadIdx.x;
  int lane = tid & 63, wave = tid >> 6;
  int r16 = lane & 15, koct = lane >> 4, msk = r16 & 7;

  f32x4 acc[2][4] = {};

  for (int k0 = 0; k0 < K; k0 += 64) {
    __syncthreads();
#pragma unroll
    for (int r = 0; r < 4; ++r) {
      int flat = r * 256 + tid;
      int row = flat >> 3;
      int grow = rowBase + row;
      if (grow >= M) grow = M - 1;
      int s = (flat & 7) ^ (row & 7);
      size_t go = (size_t)grow * K + k0 + s * 8;
      int lb = (r * 256 + wave * 64) * 8;
      async16(Ah + go, sAh + lb);
    }
#pragma unroll
    for (int r = 0; r < 2; ++r) {
      int flat = r * 256 + tid;
      int col = flat >> 3;
      int s = (flat & 7) ^ (col & 7);
      size_t go = (size_t)(colBase + col) * K + k0 + s * 8;
      int lb = (r * 256 + wave * 64) * 8;
      async16(Bth + go, sBh + lb);
    }
    __syncthreads();

#pragma unroll
    for (int kk = 0; kk < 2; ++kk) {
      bf16x8 ah[2], bh[4];
#pragma unroll
      for (int fm = 0; fm < 2; ++fm) {
        int off = (wave * 32 + fm * 16 + r16) * 64 + (((kk * 4 + koct) ^ msk) * 8);
        ah[fm] = *reinterpret_cast<const bf16x8*>(sAh + off);
      }
#pragma unroll
      for (int fn = 0; fn < 4; ++fn) {
        int off = (fn * 16 + r16) * 64 + (((kk * 4 + koct) ^ msk) * 8);
        bh[fn] = *reinterpret_cast<const bf16x8*>(sBh + off);
      }
#pragma unroll
      for (int fm = 0; fm < 2; ++fm)
#pragma unroll
        for (int fn = 0; fn < 4; ++fn)
          acc[fm][fn] = mfma16(ah[fm], bh[fn], acc[fm][fn]);
    }
  }

  float asv[4], adv[4];
#pragma unroll
  for (int fn = 0; fn < 4; ++fn) {
    asv[fn] = asrc[fn * 16 + r16];
    adv[fn] = adst[fn * 16 + r16];
  }
#pragma unroll
  for (int fm = 0; fm < 2; ++fm)
#pragma unroll
    for (int r = 0; r < 4; ++r) {
      int row = rowBase + wave * 32 + fm * 16 + koct * 4 + r;
      float ps = 0.f, pd = 0.f;
#pragma unroll
      for (int fn = 0; fn < 4; ++fn) {
        float v = acc[fm][fn][r];
        ps = fmaf(v, asv[fn], ps);
        pd = fmaf(v, adv[fn], pd);
        if (row < M) Cf[(size_t)row * Nc + fn * 16 + r16] = v;
      }
#pragma unroll
      for (int sft = 1; sft < 16; sft <<= 1) {
        ps += __shfl_xor(ps, sft);
        pd += __shfl_xor(pd, sft);
      }
      if (r16 == 0 && row < M) {
        als[row] = ps;
        ald[row] = pd;
      }
    }
}

// ------- slice-local aggregate (r14 A/B winner), 8 heads ---------------------
// 4 column-slices of 128; wave = 4 nodes x 16 col-groups. Each lane runs the
// r10 per-lane loop (8 edges/chunk, 8 gathers, own mrun) for its node,
// touching only its 128-col slice. slice = (blockIdx&7)>>1 -> XCD-pair-local
// L2 set (slice 2.56MB + src_sorted 1.3MB + alpha 0.6MB ~= 4MB). == r10 math.
__global__ __launch_bounds__(256) void agg8v4_kernel(const __bf16* __restrict__ Hb, // [N,512]
                                                     const float* __restrict__ als,
                                                     const float* __restrict__ ald,
                                                     const float* __restrict__ bias,
                                                     const int* __restrict__ row_ptr,
                                                     const int* __restrict__ src_sorted,
                                                     __bf16* __restrict__ Oh,      // [N,512]
                                                     int Nn) {
  int c8 = blockIdx.x & 7;     // XCD id (round-robin dispatch)
  int sl = c8 >> 1;            // column-slice 0..3 (2 XCDs per slice)
  int chunk = (blockIdx.x >> 3) * 2 + (c8 & 1);
  int lane = threadIdx.x & 63, wave = threadIdx.x >> 6;
  int sub = lane >> 4;         // node sub-index within wave (0..3)
  int cg = lane & 15;          // col-group within 128-col slice
  int n = chunk * 16 + wave * 4 + sub;
  bool alive = (n < Nn);
  if (!alive) n = Nn - 1;
  int head = sl * 2 + (cg >> 3);
  int colb = head * 64 + (cg & 7) * 8;  // == sl*128 + cg*8

  int start = row_ptr[n], deg = row_ptr[n + 1] - start;
  float aldn = ald[n * 8 + head];
  // wave-uniform loop bound: max deg among the wave's 4 nodes
  int dm = deg;
  dm = max(dm, __shfl_xor(dm, 16));
  dm = max(dm, __shfl_xor(dm, 32));

  float acc[8] = {};
  float ssum = 0.f;
  float mrun = 0.f;
  const __bf16* hcol = Hb + colb;
  for (int e0 = 0; e0 < dm; e0 += 8) {
    int idx[8];
    float lv[8];
    bf16x8 v[8];
#pragma unroll
    for (int i = 0; i < 8; ++i) {
      int e = e0 + i;
      if (e > deg - 1) e = deg - 1;
      idx[i] = src_sorted[start + e];
    }
#pragma unroll
    for (int i = 0; i < 8; ++i) lv[i] = als[idx[i] * 8 + head];
#pragma unroll
    for (int i = 0; i < 8; ++i)
      v[i] = *reinterpret_cast<const bf16x8*>(hcol + (size_t)idx[i] * 512);
    float lm = -INFINITY;
#pragma unroll
    for (int i = 0; i < 8; ++i) {
      float l = lv[i] + aldn;
      l = l > 0.f ? l : NEG * l;
      lv[i] = l;
      lm = fmaxf(lm, l);
    }
    if (__builtin_expect(lm > mrun + 24.f, 0)) {
      float sc = __expf(mrun - lm);
      ssum *= sc;
#pragma unroll
      for (int j = 0; j < 8; ++j) acc[j] *= sc;
      mrun = lm;
    }
#pragma unroll
    for (int i = 0; i < 8; ++i) {
      float w = (e0 + i < deg) ? __expf(lv[i] - mrun) : 0.f;
      ssum += w;
#pragma unroll
      for (int j = 0; j < 8; ++j) acc[j] = fmaf(w, (float)v[i][j], acc[j]);
    }
  }

  if (alive) {
    float inv = 1.f / (ssum + 1e-16f);
    bf16x8 vh;
#pragma unroll
    for (int j = 0; j < 8; ++j) {
      float v = acc[j] * inv + bias[colb + j];
      v = v > 0.f ? v : expm1f(v);
      vh[j] = (__bf16)v;
    }
    *reinterpret_cast<bf16x8*>(Oh + (size_t)n * 512 + colb) = vh;
  }
}

// ------- fused aggregate (1 head, one-pass) + classifier + log_softmax ------
__global__ __launch_bounds__(256) void agg1cls_kernel(const float* __restrict__ Hf, // [N,64]
                                                      const float* __restrict__ als,
                                                      const float* __restrict__ ald,
                                                      const float* __restrict__ bias,
                                                      const int* __restrict__ row_ptr,
                                                      const int* __restrict__ src_sorted,
                                                      const float* __restrict__ lw,  // [64,2]
                                                      const float* __restrict__ lb,  // [2]
                                                      float* __restrict__ out,       // [N,2]
                                                      int Nn) {
  int n = (blockIdx.x * 256 + threadIdx.x) >> 6;
  if (n >= Nn) return;
  int lane = threadIdx.x & 63;
  int start = row_ptr[n], deg = row_ptr[n + 1] - start;
  float aldn = ald[n];

  float acc = 0.f, ssum = 0.f, mrun = 0.f;
  for (int e0 = 0; e0 < deg; e0 += 8) {
    int idx[8];
    float lv[8], hv[8];
#pragma unroll
    for (int i = 0; i < 8; ++i) {
      int e = e0 + i;
      if (e > deg - 1) e = deg - 1;
      idx[i] = src_sorted[start + e];
    }
#pragma unroll
    for (int i = 0; i < 8; ++i) lv[i] = als[idx[i]];
#pragma unroll
    for (int i = 0; i < 8; ++i) hv[i] = Hf[(size_t)idx[i] * 64 + lane];
    float lm = -INFINITY;
#pragma unroll
    for (int i = 0; i < 8; ++i) {
      float l = lv[i] + aldn;
      l = l > 0.f ? l : NEG * l;
      lv[i] = l;
      lm = fmaxf(lm, l);
    }
    if (__builtin_expect(lm > mrun + 24.f, 0)) {
      float sc = __expf(mrun - lm);
      ssum *= sc;
      acc *= sc;
      mrun = lm;
    }
#pragma unroll
    for (int i = 0; i < 8; ++i) {
      float w = (e0 + i < deg) ? __expf(lv[i] - mrun) : 0.f;
      ssum += w;
      acc = fmaf(w, hv[i], acc);
    }
  }
  float o = acc / (ssum + 1e-16f) + bias[lane];

  float p0 = o * lw[lane * 2 + 0];
  float p1 = o * lw[lane * 2 + 1];
  for (int s = 32; s; s >>= 1) {
    p0 += __shfl_xor(p0, s);
    p1 += __shfl_xor(p1, s);
  }
  if (lane == 0) {
    p0 += lb[0];
    p1 += lb[1];
    float mx = fmaxf(p0, p1);
    float lse = mx + logf(expf(p0 - mx) + expf(p1 - mx));
    out[n * 2 + 0] = p0 - lse;
    out[n * 2 + 1] = p1 - lse;
  }
}

extern "C" void kernel_launch(void* const* d_in, const int* in_sizes, int n_in,
                              void* d_out, int out_size, void* d_ws, size_t ws_size,
                              hipStream_t stream) {
  (void)n_in; (void)out_size; (void)ws_size;
  const float* x     = (const float*)d_in[0];
  const int*   ei    = (const int*)d_in[1];
  const float* W1    = (const float*)d_in[2];
  const float* asrc1 = (const float*)d_in[3];
  const float* adst1 = (const float*)d_in[4];
  const float* b1    = (const float*)d_in[5];
  const float* W2    = (const float*)d_in[6];
  const float* asrc2 = (const float*)d_in[7];
  const float* adst2 = (const float*)d_in[8];
  const float* b2    = (const float*)d_in[9];
  const float* W3    = (const float*)d_in[10];
  const float* asrc3 = (const float*)d_in[11];
  const float* adst3 = (const float*)d_in[12];
  const float* b3    = (const float*)d_in[13];
  const float* linW  = (const float*)d_in[14];
  const float* linb  = (const float*)d_in[15];
  float* out = (float*)d_out;

  int Nn = in_sizes[0] / 256;
  int E  = in_sizes[1] / 2;
  int E2 = E + Nn;

  char* w = (char*)d_ws;
  auto carve = [&](size_t bytes) {
    char* p = w;
    w += (bytes + 63) & ~(size_t)63;
    return p;
  };
  __bf16* xsh  = (__bf16*)carve((size_t)Nn * 256 * 2);
  __bf16* xsl  = (__bf16*)carve((size_t)Nn * 256 * 2);
  __bf16* Ahb  = (__bf16*)carve((size_t)Nn * 512 * 2);
  __bf16* Hb16 = (__bf16*)carve((size_t)Nn * 512 * 2);
  float*  Hb3  = (float*)carve((size_t)Nn * 64 * 4);
  float*  als  = (float*)carve((size_t)Nn * 8 * 4);
  float*  ald  = (float*)carve((size_t)Nn * 8 * 4);
  __bf16* W1th = (__bf16*)carve(256 * 512 * 2);
  __bf16* W2th = (__bf16*)carve(512 * 512 * 2);
  __bf16* W3th = (__bf16*)carve(512 * 64 * 2);
  int* counts     = (int*)carve((size_t)Nn * 4);
  int* cursor     = (int*)carve((size_t)Nn * 4);
  int* row_ptr    = (int*)carve(((size_t)Nn + 1) * 4);
  int* src_sorted = (int*)carve((size_t)E2 * 4);

  int prep_total = Nn + Nn * 256 + 256 * 512 + 512 * 512 + 512 * 64;
  prep_kernel<<<(prep_total + 255) / 256, 256, 0, stream>>>(
      x, xsh, xsl, W1, W1th, W2, W2th, W3, W3th, counts, Nn);
  count_kernel<<<(E2 + 255) / 256, 256, 0, stream>>>(ei, counts, E, Nn);
  scan_kernel<<<1, 1024, 0, stream>>>(counts, row_ptr, cursor, Nn, E2);
  scatter_kernel<<<(E2 + 255) / 256, 256, 0, stream>>>(ei, cursor, src_sorted, E, Nn);

  int gx64 = (Nn + 63) / 64;           // 157 row-panels for v3
  int PX3 = (gx64 + 7) / 8;            // 20
  int nblk3 = 8 * PX3 * 4;             // 640 blocks
  int gx128 = (Nn + 127) / 128;        // 79 (layer 3)
  int ga = (Nn + 3) / 4;
  int gv4 = ((Nn + 31) / 32) * 8;      // v4 grid: 16 nodes/block

  // layer 1: 256 -> 8x64 concat (split-A, alpha fused)
  gemm_v3<true><<<nblk3, 256, 0, stream>>>(xsh, xsl, W1th, Hb16,
                                           asrc1, adst1, als, ald, Nn, 256, 512, PX3);
  agg8v4_kernel<<<gv4, 256, 0, stream>>>(Hb16, als, ald, b1, row_ptr, src_sorted, Ahb, Nn);
  // layer 2: 512 -> 8x64 concat (1-pass A)
  gemm_v3<false><<<nblk3, 256, 0, stream>>>(Ahb, nullptr, W2th, Hb16,
                                            asrc2, adst2, als, ald, Nn, 512, 512, PX3);
  agg8v4_kernel<<<gv4, 256, 0, stream>>>(Hb16, als, ald, b2, row_ptr, src_sorted, Ahb, Nn);
  // layer 3: 512 -> 64, 1 head (1-pass A, fp32 out, alpha fused)
  gemm_v2<<<gx128, 256, 0, stream>>>(Ahb, W3th, Hb3,
                                     asrc3, adst3, als, ald, Nn, 512, 64);
  // aggregate + classifier + log_softmax
  agg1cls_kernel<<<ga, 256, 0, stream>>>(Hb3, als, ald, b3, row_ptr, src_sorted,
                                         linW, linb, out, Nn);
}